// Round 9
// baseline (193.971 us; speedup 1.0000x reference)
//
#include <hip/hip_runtime.h>
#include <math.h>

#define N_NODES 200000
#define NF 128
#define NT 32
#define NS 32
#define NG 128
#define BTILE 4         // MFMA tiles (64 nodes each) per block
#define BNODES 256      // nodes per block
#define NBLOCKS 782     // 781 full + 1 partial (64 nodes)
#define HPAD 33         // hist/corr stride; slot 32 = dummy overflow bin

typedef short bf16x8 __attribute__((ext_vector_type(8)));
typedef float floatx4 __attribute__((ext_vector_type(4)));

__device__ __forceinline__ float rcp_fast(float x) { return __builtin_amdgcn_rcpf(x); }

// split fp32 into bf16 hi + bf16 lo (RTN both): f ~= hi + lo to ~2^-17 rel
__device__ __forceinline__ void split_bf16(float f, unsigned short& h, unsigned short& l) {
    unsigned u  = __float_as_uint(f);
    unsigned r  = u + 0x7FFFu + ((u >> 16) & 1u);
    unsigned hb = r & 0xFFFF0000u;
    h = (unsigned short)(hb >> 16);
    float rem = f - __uint_as_float(hb);
    unsigned u2 = __float_as_uint(rem);
    unsigned r2 = u2 + 0x7FFFu + ((u2 >> 16) & 1u);
    l = (unsigned short)(r2 >> 16);
}

__device__ __forceinline__ void split8(float4 a, float4 b, bf16x8& h8, bf16x8& l8) {
    unsigned short h[8], l[8];
    split_bf16(a.x, h[0], l[0]); split_bf16(a.y, h[1], l[1]);
    split_bf16(a.z, h[2], l[2]); split_bf16(a.w, h[3], l[3]);
    split_bf16(b.x, h[4], l[4]); split_bf16(b.y, h[5], l[5]);
    split_bf16(b.z, h[6], l[6]); split_bf16(b.w, h[7], l[7]);
    h8 = (bf16x8){(short)h[0],(short)h[1],(short)h[2],(short)h[3],
                  (short)h[4],(short)h[5],(short)h[6],(short)h[7]};
    l8 = (bf16x8){(short)l[0],(short)l[1],(short)l[2],(short)l[3],
                  (short)l[4],(short)l[5],(short)l[6],(short)l[7]};
}

// ---- prep: split v (32x128 fp32) into bf16 hi/lo planes in d_ws ----
__global__ __launch_bounds__(256)
void prep_v(const float* __restrict__ v,
            unsigned short* __restrict__ vh,
            unsigned short* __restrict__ vl)
{
    int j = blockIdx.x * 256 + threadIdx.x;
    if (j >= NT * NF / 4) return;
    float4 val = ((const float4*)v)[j];
    unsigned short h0,h1,h2,h3,l0,l1,l2,l3;
    split_bf16(val.x, h0, l0); split_bf16(val.y, h1, l1);
    split_bf16(val.z, h2, l2); split_bf16(val.w, h3, l3);
    ((ushort4*)vh)[j] = make_ushort4(h0, h1, h2, h3);
    ((ushort4*)vl)[j] = make_ushort4(l0, l1, l2, l3);
}

__global__ __launch_bounds__(256, 4)
void ect_fused(const float* __restrict__ x,
               const int* __restrict__ batch,
               const unsigned short* __restrict__ vh,   // [32][128] bf16, L2-hot
               const unsigned short* __restrict__ vl,
               float* __restrict__ out)
{
    __shared__ unsigned hist[NT * HPAD];   // 4224 B
    __shared__ float    corr[NT * HPAD];   // 4224 B
    __shared__ float    cntw[4];           // per-wave node counts at flush

    const int tid  = threadIdx.x;
    const int blk  = blockIdx.x;
    const int w    = tid >> 6;
    const int lane = tid & 63;
    const int mrow = lane & 15;
    const int quad = lane >> 4;

    const int base   = blk * BNODES;
    const int nnodes = min(BNODES, N_NODES - base);
    const int ntiles = nnodes >> 6;        // 4, or 1 for the last block

    // my node label for pad-count ballots (clamped load; validity mask separate)
    const int  myidx   = base + tid;
    const int  mylabel = batch[(myidx < N_NODES) ? myidx : (N_NODES - 1)];
    const bool cvalid  = (tid < nnodes);

    int gp = batch[base];                  // current graph (block-uniform)

    for (int i = tid; i < NT * HPAD; i += 256) { hist[i] = 0u; corr[i] = 0.0f; }
    __syncthreads();

    const int b0off = mrow * NF + quad * 8;          // thetas 0..15
    const int b1off = (16 + mrow) * NF + quad * 8;   // thetas 16..31

    const float inv_dlin = 14.090909090909092f;  // 31/2.2
    const float Lw       = 10.23848093f;         // SCALE * dlin * log2(e)
    const float dlin     = 2.2f / 31.0f;
    const float L        = 144.26950408889634f;  // SCALE * log2(e)

    const int ft = tid & 31;   // flush ownership: (t=ft, s=sb+8k)
    const int sb = tid >> 5;

    for (int tile = 0; tile < ntiles; ++tile) {
        const int trow = base + tile * 64;

        // ---- A fragments straight from global; split to bf16 hi/lo ----
        const float* __restrict__ xrow = x + (size_t)(trow + w * 16 + mrow) * NF + quad * 8;
        bf16x8 ah[4], al[4];
        #pragma unroll
        for (int s = 0; s < 4; ++s) {
            float4 a0 = *(const float4*)&xrow[s * 32];
            float4 a1 = *(const float4*)&xrow[s * 32 + 4];
            split8(a0, a1, ah[s], al[s]);
        }

        // ---- MFMA: B fragments from pre-split global v (L1-hot after tile 0) ----
        floatx4 acc0 = {0.f, 0.f, 0.f, 0.f};
        floatx4 acc1 = {0.f, 0.f, 0.f, 0.f};
        #pragma unroll
        for (int s = 0; s < 4; ++s) {
            bf16x8 bh0 = *(const bf16x8*)&vh[b0off + s * 32];
            bf16x8 bl0 = *(const bf16x8*)&vl[b0off + s * 32];
            bf16x8 bh1 = *(const bf16x8*)&vh[b1off + s * 32];
            bf16x8 bl1 = *(const bf16x8*)&vl[b1off + s * 32];
            acc0 = __builtin_amdgcn_mfma_f32_16x16x32_bf16(ah[s], bh0, acc0, 0, 0, 0);
            acc0 = __builtin_amdgcn_mfma_f32_16x16x32_bf16(ah[s], bl0, acc0, 0, 0, 0);
            acc0 = __builtin_amdgcn_mfma_f32_16x16x32_bf16(al[s], bh0, acc0, 0, 0, 0);
            acc1 = __builtin_amdgcn_mfma_f32_16x16x32_bf16(ah[s], bh1, acc1, 0, 0, 0);
            acc1 = __builtin_amdgcn_mfma_f32_16x16x32_bf16(ah[s], bl1, acc1, 0, 0, 0);
            acc1 = __builtin_amdgcn_mfma_f32_16x16x32_bf16(al[s], bh1, acc1, 0, 0, 0);
        }
        // C/D layout: col = lane&15 (theta), row = quad*4 + reg (node-in-16-tile)

        int nlabel[4];
        #pragma unroll
        for (int reg = 0; reg < 4; ++reg)
            nlabel[reg] = batch[trow + w * 16 + quad * 4 + reg];
        const int tlast = batch[trow + 63];   // block-uniform

        while (true) {
            // sweep this tile's cells belonging to gp (no barrier; LDS atomics)
            #pragma unroll
            for (int reg = 0; reg < 4; ++reg) {
                if (nlabel[reg] == gp) {
                    #pragma unroll
                    for (int half = 0; half < 2; ++half) {
                        int   t = half ? (16 + mrow) : mrow;
                        float h = half ? acc1[reg] : acc0[reg];
                        float z = fmaf(h, inv_dlin, 15.5f);      // (h + 1.1)/dlin
                        int s_up = (int)ceilf(z);
                        s_up = min(max(s_up, 0), 32);
                        atomicAdd(&hist[t * HPAD + s_up], 1u);
                        int s0 = (int)ceilf(z - 1.45f);
                        #pragma unroll
                        for (int i2 = 0; i2 < 3; ++i2) {
                            int s = s0 + i2;
                            float e   = __builtin_amdgcn_exp2f(Lw * (z - (float)s));
                            float sig = rcp_fast(1.0f + e);
                            float stp = (s >= s_up) ? 1.0f : 0.0f;
                            if (s >= 0 && s <= 31) atomicAdd(&corr[t * HPAD + s], sig - stp);
                        }
                    }
                }
            }
            if (tlast <= gp) break;   // graph continues into later tiles (or tile done)

            // ---- flush gp (graph boundary inside this tile) ----
            __syncthreads();
            {
                unsigned long long m = __ballot(cvalid && (mylabel == gp));
                if (lane == 0) cntw[w] = (float)__popcll(m);
            }
            {   // inclusive prefix of hist over s, folded into corr
                const int grp = tid >> 5;
                const int s   = tid & 31;
                for (int row = grp; row < NT; row += 8) {
                    float val = (float)hist[row * HPAD + s];
                    #pragma unroll
                    for (int d = 1; d < 32; d <<= 1) {
                        float nbr = __shfl_up(val, d, 32);
                        if (s >= d) val += nbr;
                    }
                    corr[row * HPAD + s] += val;
                }
            }
            __syncthreads();
            float cnt = cntw[0] + cntw[1] + cntw[2] + cntw[3];
            #pragma unroll
            for (int k = 0; k < 4; ++k) {
                int s = sb + 8 * k;
                float lin_s = -1.1f + (float)s * dlin;
                float cs  = rcp_fast(1.0f + __builtin_amdgcn_exp2f(L * (1.1f - lin_s)));
                float val = corr[ft * HPAD + s] - cnt * cs;
                atomicAdd(&out[(size_t)gp * (NS * NT) + s * NT + ft], val);
                // zero exactly the cells this thread just consumed (race-free)
                corr[ft * HPAD + s] = 0.0f;
                hist[ft * HPAD + s] = 0u;
            }
            if (sb == 0) { hist[ft * HPAD + 32] = 0u; corr[ft * HPAD + 32] = 0.0f; }
            __syncthreads();
            ++gp;
        }
    }

    // ---- final flush ----
    __syncthreads();
    {
        unsigned long long m = __ballot(cvalid && (mylabel == gp));
        if (lane == 0) cntw[w] = (float)__popcll(m);
    }
    {
        const int grp = tid >> 5;
        const int s   = tid & 31;
        for (int row = grp; row < NT; row += 8) {
            float val = (float)hist[row * HPAD + s];
            #pragma unroll
            for (int d = 1; d < 32; d <<= 1) {
                float nbr = __shfl_up(val, d, 32);
                if (s >= d) val += nbr;
            }
            corr[row * HPAD + s] += val;
        }
    }
    __syncthreads();
    float cnt = cntw[0] + cntw[1] + cntw[2] + cntw[3];
    #pragma unroll
    for (int k = 0; k < 4; ++k) {
        int s = sb + 8 * k;
        float lin_s = -1.1f + (float)s * dlin;
        float cs  = rcp_fast(1.0f + __builtin_amdgcn_exp2f(L * (1.1f - lin_s)));
        float val = corr[ft * HPAD + s] - cnt * cs;
        atomicAdd(&out[(size_t)gp * (NS * NT) + s * NT + ft], val);
    }
}

extern "C" void kernel_launch(void* const* d_in, const int* in_sizes, int n_in,
                              void* d_out, int out_size, void* d_ws, size_t ws_size,
                              hipStream_t stream) {
    const float* x     = (const float*)d_in[0];
    const int*   batch = (const int*)d_in[1];
    const float* v     = (const float*)d_in[3];
    float*       out   = (float*)d_out;

    unsigned short* vh = (unsigned short*)d_ws;   // 32*128 bf16 = 8 KB
    unsigned short* vl = vh + NT * NF;            // 8 KB

    hipMemsetAsync(d_out, 0, (size_t)out_size * sizeof(float), stream);
    prep_v<<<dim3(4), dim3(256), 0, stream>>>(v, vh, vl);
    ect_fused<<<dim3(NBLOCKS), dim3(256), 0, stream>>>(x, batch, vh, vl, out);
}